// Round 1
// 295.835 us; speedup vs baseline: 1.0081x; 1.0081x over previous
//
#include <hip/hip_runtime.h>
#include <hip/hip_fp16.h>
#include <stdint.h>

// Problem constants (fixed: M=N=K=4096).
// Harness buffer reality (proven r5-r8): x,lut,out are float32; packed_weight
// is int32 holding ONE byte per element (hi nibble = even k, lo nibble = odd k).
#define M_DIM 4096
#define N_DIM 4096
#define K_DIM 4096
#define BM 128
#define BN 128
#define BK 32
#define KW (K_DIM / 2)
#define WS_XH_BYTES ((size_t)M_DIM * K_DIM * 2)  // 32 MB: x as fp16
#define WS_WH_BYTES ((size_t)N_DIM * K_DIM * 2)  // 32 MB: W as fp16

typedef _Float16 half8 __attribute__((ext_vector_type(8)));   // 4 VGPRs (MFMA A/B)
typedef float f32x4 __attribute__((ext_vector_type(4)));      // MFMA accumulator

__device__ __forceinline__ uint32_t pk2(float a, float b) {
  // packed f32->f16 RTZ (exact: every input value is fp16-representable)
  auto h = __builtin_amdgcn_cvt_pkrtz(a, b);  // a -> low halfword
  return __builtin_bit_cast(uint32_t, h);
}

// Dequant one packed byte -> u32 (fp16 even-k | fp16 odd-k << 16) via v_perm
// byte lookup in an 8-byte magnitude pool (fp16 high bytes of lut[0..7]; fp4
// values have zero fp16 low byte). Sign: lut[8..15] == -lut[0..7], nibble
// bit 3 ORs into the fp16 sign bit.  [proven bit-exact r6-r8]
__device__ __forceinline__ uint32_t dq(uint32_t b, uint32_t ph, uint32_t pl) {
#if __has_builtin(__builtin_amdgcn_perm)
  const uint32_t sel = ((b & 0x70u) << 4) | ((b & 0x07u) << 24);
  uint32_t v = __builtin_amdgcn_perm(ph, pl, sel);  // bytes 4-7 = ph, 0-3 = pl
#else
  const uint64_t pool = ((uint64_t)ph << 32) | pl;
  const uint32_t mh = (uint32_t)(pool >> (((b >> 4) & 7u) * 8)) & 0xFFu;
  const uint32_t ml = (uint32_t)(pool >> ((b & 7u) * 8)) & 0xFFu;
  uint32_t v = (mh << 8) | (ml << 24);
#endif
  const uint32_t sg = ((b & 0x88u) * 0x10000100u) & 0x80008000u;  // b7->15, b3->31
  return v | sg;
}

// Magnitude pool from runtime LUT (fp16 high bytes of lut[0..7]).
__device__ __forceinline__ void lut_pool(const float* __restrict__ lutf,
                                         uint32_t& ph, uint32_t& pl) {
  const uint32_t h01 = pk2(lutf[0], lutf[1]);
  const uint32_t h23 = pk2(lutf[2], lutf[3]);
  const uint32_t h45 = pk2(lutf[4], lutf[5]);
  const uint32_t h67 = pk2(lutf[6], lutf[7]);
#if __has_builtin(__builtin_amdgcn_perm)
  pl = __builtin_amdgcn_perm(h23, h01, 0x07050301u);
  ph = __builtin_amdgcn_perm(h67, h45, 0x07050301u);
#else
  pl = ((h01 >> 8) & 0xFFu) | ((h01 >> 24) << 8) |
       (((h23 >> 8) & 0xFFu) << 16) | ((h23 >> 24) << 24);
  ph = ((h45 >> 8) & 0xFFu) | ((h45 >> 24) << 8) |
       (((h67 >> 8) & 0xFFu) << 16) | ((h67 >> 24) << 24);
#endif
}

// Pre-pass 1: x f32 [M,K] -> fp16 bits in d_ws. 2 float4 in, 1 uint4 out/thread.
__global__ __launch_bounds__(256) void cvt_x_kernel(const float4* __restrict__ xin,
                                                    uint4* __restrict__ xout) {
  const int i = blockIdx.x * 256 + threadIdx.x;   // uint4 index
  const float4 v0 = xin[2 * i];
  const float4 v1 = xin[2 * i + 1];
  xout[i] = make_uint4(pk2(v0.x, v0.y), pk2(v0.z, v0.w),
                       pk2(v1.x, v1.y), pk2(v1.z, v1.w));
}

// Pre-pass 2 (round 10): W dequant hoisted out of the GEMM K-loop.
// packed int32 [N, K/2] (one byte/elem) -> fp16 [N, K]. dq() word layout is
// exactly the [N,K] fp16 word: even k in low half, odd k in high half.
// 32 MB read + 32 MB write; W-f16 GEMM traffic == packed traffic (both 32 MB).
__global__ __launch_bounds__(256) void wdq_kernel(const int4* __restrict__ pin,
                                                  uint4* __restrict__ wout,
                                                  const float* __restrict__ lutf) {
  uint32_t ph, pl;
  lut_pool(lutf, ph, pl);
  const int i = blockIdx.x * 256 + threadIdx.x;   // int4 index (4 packed bytes)
  const int4 w = pin[i];
  wout[i] = make_uint4(dq(w.x, ph, pl), dq(w.y, ph, pl),
                       dq(w.z, ph, pl), dq(w.w, ph, pl));
}

// y[m][n] = sum_k x[m][k] * W[n][k]; pure-f16 GEMM, both operands pre-converted
// in d_ws. 128x128 tile, BK=32, 4 waves (2x2), 4x4 grid of 16x16x32 f16 MFMA.
// XOR bank swizzle (proven r9): 16B chunk c of row r holds k-chunk
// (c ^ ((r>>1)&3)); GLL source-permute keeps the LDS dest contiguous, frag
// reads land 2-way/bank (free).
__global__ __launch_bounds__(256, 2) void f16gemm_kernel(
    const uint8_t* __restrict__ xh,    // fp16 bits [M, K] (ws + 0)
    const uint8_t* __restrict__ wh,    // fp16 bits [N, K] (ws + 32MB)
    float* __restrict__ out)           // [M, N] float32
{
  __shared__ uint16_t ldsA[BM * BK];   // [128][32] fp16, swizzled chunks
  __shared__ uint16_t ldsB[BN * BK];   // [128][32] fp16, swizzled chunks

  const int tid  = threadIdx.x;
  const int lane = tid & 63;
  const int wave = tid >> 6;
  const int wm   = wave >> 1;          // 64-row half of M tile
  const int wn   = wave & 1;           // 64-col half of N tile
  const int m0 = blockIdx.y * BM;
  const int n0 = blockIdx.x * BN;

  f32x4 acc[4][4];
#pragma unroll
  for (int i = 0; i < 4; ++i)
#pragma unroll
    for (int j = 0; j < 4; ++j) acc[i][j] = (f32x4){0.f, 0.f, 0.f, 0.f};

  const uint8_t* xbase = xh + (size_t)m0 * K_DIM * 2;
  const uint8_t* wbase = wh + (size_t)n0 * K_DIM * 2;

  for (int kt = 0; kt < K_DIM / BK; ++kt) {
    __syncthreads();  // prev compute done before LDS overwrite

    // ---- Stage A and B: 2x 128x32 fp16 = 2x 8 KB via global_load_lds ----
    // LDS slot (row, c16) receives global k-chunk (c16 ^ ((row>>1)&3)).
#pragma unroll
    for (int s = 0; s < 2; ++s) {
      const int idx = tid + s * 256;        // 0..511 16B slots (contiguous/wave)
      const int row = idx >> 2;
      const int c16 = idx & 3;
      const int g16 = c16 ^ ((row >> 1) & 3);
      const size_t goff = ((size_t)row * K_DIM + kt * BK) * 2 + g16 * 16;
      __builtin_amdgcn_global_load_lds(
          (const __attribute__((address_space(1))) uint32_t*)(xbase + goff),
          (__attribute__((address_space(3))) uint32_t*)((uint8_t*)ldsA + (size_t)idx * 16),
          16, 0, 0);
      __builtin_amdgcn_global_load_lds(
          (const __attribute__((address_space(1))) uint32_t*)(wbase + goff),
          (__attribute__((address_space(3))) uint32_t*)((uint8_t*)ldsB + (size_t)idx * 16),
          16, 0, 0);
    }

    __syncthreads();  // drains vmcnt (GLL)

    // ---- Compute: 4 A-frags x 4 B-frags, 16 MFMAs ----
    // Frag (row, q) lives at chunk q ^ ((row>>1)&3).
    const int q = lane >> 4;
    half8 af[4], bfr[4];
#pragma unroll
    for (int i = 0; i < 4; ++i) {
      const int row = wm * 64 + i * 16 + (lane & 15);
      const uint16_t* pa = ldsA + row * BK + (q ^ ((row >> 1) & 3)) * 8;
      af[i] = *(const half8*)pa;
    }
#pragma unroll
    for (int j = 0; j < 4; ++j) {
      const int row = wn * 64 + j * 16 + (lane & 15);
      const uint16_t* pb = ldsB + row * BK + (q ^ ((row >> 1) & 3)) * 8;
      bfr[j] = *(const half8*)pb;
    }
#pragma unroll
    for (int i = 0; i < 4; ++i)
#pragma unroll
      for (int j = 0; j < 4; ++j)
        acc[i][j] = __builtin_amdgcn_mfma_f32_16x16x32_f16(af[i], bfr[j], acc[i][j], 0, 0, 0);
  }

  // ---- Epilogue: C/D layout col(n) = lane&15, row(m) = (lane>>4)*4 + reg ----
  const int mb = m0 + wm * 64 + (lane >> 4) * 4;
  const int nb = n0 + wn * 64 + (lane & 15);
#pragma unroll
  for (int i = 0; i < 4; ++i)
#pragma unroll
    for (int j = 0; j < 4; ++j)
#pragma unroll
      for (int r = 0; r < 4; ++r)
        out[(size_t)(mb + i * 16 + r) * N_DIM + (nb + j * 16)] = acc[i][j][r];
}

// Fallback (r9 champion structure): in-loop B dequant, used only if d_ws is
// too small to hold both fp16 operands.
__global__ __launch_bounds__(256, 2) void fp4gemm_kernel(
    const uint8_t* __restrict__ xh,    // fp16 bits [M, K] (in d_ws)
    const int* __restrict__ pw,        // [N, K/2] int32, one packed byte each
    const float* __restrict__ lutf,    // 16 float LUT values
    float* __restrict__ out)           // [M, N] float32
{
  __shared__ uint16_t ldsA[BM * BK];
  __shared__ uint16_t ldsB[BN * BK];

  const int tid  = threadIdx.x;
  const int lane = tid & 63;
  const int wave = tid >> 6;
  const int wm   = wave >> 1;
  const int wn   = wave & 1;
  const int m0 = blockIdx.y * BM;
  const int n0 = blockIdx.x * BN;

  uint32_t ph, pl;
  lut_pool(lutf, ph, pl);

  f32x4 acc[4][4];
#pragma unroll
  for (int i = 0; i < 4; ++i)
#pragma unroll
    for (int j = 0; j < 4; ++j) acc[i][j] = (f32x4){0.f, 0.f, 0.f, 0.f};

  const int rowB  = tid >> 1;
  const int halfB = tid & 1;
  const int swzB  = (rowB >> 1) & 3;

  for (int kt = 0; kt < K_DIM / BK; ++kt) {
    __syncthreads();

#pragma unroll
    for (int s = 0; s < 2; ++s) {
      const int idx = tid + s * 256;
      const int row = idx >> 2;
      const int c16 = idx & 3;
      const int g16 = c16 ^ ((row >> 1) & 3);
      const uint8_t* gp = xh + ((size_t)(m0 + row) * K_DIM + kt * BK) * 2 + g16 * 16;
      uint8_t* lp = (uint8_t*)ldsA + (size_t)idx * 16;
      __builtin_amdgcn_global_load_lds(
          (const __attribute__((address_space(1))) uint32_t*)gp,
          (__attribute__((address_space(3))) uint32_t*)lp, 16, 0, 0);
    }

    {
      const int* gp = pw + (size_t)(n0 + rowB) * KW + kt * (BK / 2) + halfB * 8;
      const int4 wA = ((const int4*)gp)[0];
      const int4 wB = ((const int4*)gp)[1];
      uint8_t* base = (uint8_t*)ldsB + rowB * 64;
      *(uint4*)(base + ((halfB * 2 + 0) ^ swzB) * 16) =
          make_uint4(dq(wA.x, ph, pl), dq(wA.y, ph, pl),
                     dq(wA.z, ph, pl), dq(wA.w, ph, pl));
      *(uint4*)(base + ((halfB * 2 + 1) ^ swzB) * 16) =
          make_uint4(dq(wB.x, ph, pl), dq(wB.y, ph, pl),
                     dq(wB.z, ph, pl), dq(wB.w, ph, pl));
    }

    __syncthreads();

    const int q = lane >> 4;
    half8 af[4], bfr[4];
#pragma unroll
    for (int i = 0; i < 4; ++i) {
      const int row = wm * 64 + i * 16 + (lane & 15);
      const uint16_t* pa = ldsA + row * BK + (q ^ ((row >> 1) & 3)) * 8;
      af[i] = *(const half8*)pa;
    }
#pragma unroll
    for (int j = 0; j < 4; ++j) {
      const int row = wn * 64 + j * 16 + (lane & 15);
      const uint16_t* pb = ldsB + row * BK + (q ^ ((row >> 1) & 3)) * 8;
      bfr[j] = *(const half8*)pb;
    }
#pragma unroll
    for (int i = 0; i < 4; ++i)
#pragma unroll
      for (int j = 0; j < 4; ++j)
        acc[i][j] = __builtin_amdgcn_mfma_f32_16x16x32_f16(af[i], bfr[j], acc[i][j], 0, 0, 0);
  }

  const int mb = m0 + wm * 64 + (lane >> 4) * 4;
  const int nb = n0 + wn * 64 + (lane & 15);
#pragma unroll
  for (int i = 0; i < 4; ++i)
#pragma unroll
    for (int j = 0; j < 4; ++j)
#pragma unroll
      for (int r = 0; r < 4; ++r)
        out[(size_t)(mb + i * 16 + r) * N_DIM + (nb + j * 16)] = acc[i][j][r];
}

extern "C" void kernel_launch(void* const* d_in, const int* in_sizes, int n_in,
                              void* d_out, int out_size, void* d_ws, size_t ws_size,
                              hipStream_t stream) {
  // Size-based dispatch (element counts are dtype-independent and unique).
  const void* px = nullptr; const void* ppw = nullptr; const void* plut = nullptr;
  for (int i = 0; i < n_in; ++i) {
    const long s = in_sizes[i];
    if (s == (long)M_DIM * K_DIM) px = d_in[i];
    else if (s == (long)N_DIM * KW) ppw = d_in[i];
    else if (s == 16) plut = d_in[i];
  }
  if (!px || !ppw || !plut) { px = d_in[0]; ppw = d_in[1]; plut = d_in[2]; }

  dim3 grid(N_DIM / BN, M_DIM / BM);  // (32, 32)

  // x f32 -> fp16 into ws[0, 32MB).
  cvt_x_kernel<<<(M_DIM * K_DIM / 8) / 256, 256, 0, stream>>>(
      (const float4*)px, (uint4*)d_ws);

  if (ws_size >= WS_XH_BYTES + WS_WH_BYTES) {
    // W fp4 -> fp16 into ws[32MB, 64MB), then pure-f16 GEMM (dequant off the
    // K-loop critical path; W-f16 bytes == packed bytes, no extra HBM traffic).
    uint8_t* wh = (uint8_t*)d_ws + WS_XH_BYTES;
    wdq_kernel<<<(N_DIM * KW / 4) / 256, 256, 0, stream>>>(
        (const int4*)ppw, (uint4*)wh, (const float*)plut);
    f16gemm_kernel<<<grid, dim3(256), 0, stream>>>(
        (const uint8_t*)d_ws, wh, (float*)d_out);
  } else {
    // Workspace too small: r9 fused-dequant champion path.
    fp4gemm_kernel<<<grid, dim3(256), 0, stream>>>(
        (const uint8_t*)d_ws, (const int*)ppw, (const float*)plut, (float*)d_out);
  }
}

// Round 3
// 268.884 us; speedup vs baseline: 1.1091x; 1.1002x over previous
//
#include <hip/hip_runtime.h>
#include <hip/hip_fp16.h>
#include <stdint.h>

// Problem constants (fixed: M=N=K=4096).
// Harness buffer reality (proven r5-r8): x,lut,out are float32; packed_weight
// is int32 holding ONE byte per element (hi nibble = even k, lo nibble = odd k).
#define M_DIM 4096
#define N_DIM 4096
#define K_DIM 4096
#define KW (K_DIM / 2)
#define WS_XH_BYTES ((size_t)M_DIM * K_DIM * 2)  // 32 MB: x as fp16
#define WS_WH_BYTES ((size_t)N_DIM * K_DIM * 2)  // 32 MB: W as fp16

typedef _Float16 half8 __attribute__((ext_vector_type(8)));   // 4 VGPRs (MFMA A/B)
typedef float f32x4 __attribute__((ext_vector_type(4)));      // MFMA accumulator

__device__ __forceinline__ uint32_t pk2(float a, float b) {
  // packed f32->f16 RTZ (exact: every input value is fp16-representable)
  auto h = __builtin_amdgcn_cvt_pkrtz(a, b);  // a -> low halfword
  return __builtin_bit_cast(uint32_t, h);
}

// Dequant one packed byte -> u32 (fp16 even-k | fp16 odd-k << 16) via v_perm
// byte lookup in an 8-byte magnitude pool. [proven bit-exact r6-r8]
__device__ __forceinline__ uint32_t dq(uint32_t b, uint32_t ph, uint32_t pl) {
#if __has_builtin(__builtin_amdgcn_perm)
  const uint32_t sel = ((b & 0x70u) << 4) | ((b & 0x07u) << 24);
  uint32_t v = __builtin_amdgcn_perm(ph, pl, sel);  // bytes 4-7 = ph, 0-3 = pl
#else
  const uint64_t pool = ((uint64_t)ph << 32) | pl;
  const uint32_t mh = (uint32_t)(pool >> (((b >> 4) & 7u) * 8)) & 0xFFu;
  const uint32_t ml = (uint32_t)(pool >> ((b & 7u) * 8)) & 0xFFu;
  uint32_t v = (mh << 8) | (ml << 24);
#endif
  const uint32_t sg = ((b & 0x88u) * 0x10000100u) & 0x80008000u;  // b7->15, b3->31
  return v | sg;
}

__device__ __forceinline__ void lut_pool(const float* __restrict__ lutf,
                                         uint32_t& ph, uint32_t& pl) {
  const uint32_t h01 = pk2(lutf[0], lutf[1]);
  const uint32_t h23 = pk2(lutf[2], lutf[3]);
  const uint32_t h45 = pk2(lutf[4], lutf[5]);
  const uint32_t h67 = pk2(lutf[6], lutf[7]);
#if __has_builtin(__builtin_amdgcn_perm)
  pl = __builtin_amdgcn_perm(h23, h01, 0x07050301u);
  ph = __builtin_amdgcn_perm(h67, h45, 0x07050301u);
#else
  pl = ((h01 >> 8) & 0xFFu) | ((h01 >> 24) << 8) |
       (((h23 >> 8) & 0xFFu) << 16) | ((h23 >> 24) << 24);
  ph = ((h45 >> 8) & 0xFFu) | ((h45 >> 24) << 8) |
       (((h67 >> 8) & 0xFFu) << 16) | ((h67 >> 24) << 24);
#endif
}

// Pre-pass 1: x f32 [M,K] -> fp16 bits in d_ws.
__global__ __launch_bounds__(256) void cvt_x_kernel(const float4* __restrict__ xin,
                                                    uint4* __restrict__ xout) {
  const int i = blockIdx.x * 256 + threadIdx.x;   // uint4 index
  const float4 v0 = xin[2 * i];
  const float4 v1 = xin[2 * i + 1];
  xout[i] = make_uint4(pk2(v0.x, v0.y), pk2(v0.z, v0.w),
                       pk2(v1.x, v1.y), pk2(v1.z, v1.w));
}

// Pre-pass 2: W packed fp4 -> fp16 [N,K] (dequant hoisted off the K-loop, r10).
__global__ __launch_bounds__(256) void wdq_kernel(const int4* __restrict__ pin,
                                                  uint4* __restrict__ wout,
                                                  const float* __restrict__ lutf) {
  uint32_t ph, pl;
  lut_pool(lutf, ph, pl);
  const int i = blockIdx.x * 256 + threadIdx.x;   // int4 index (4 packed bytes)
  const int4 w = pin[i];
  wout[i] = make_uint4(dq(w.x, ph, pl), dq(w.y, ph, pl),
                       dq(w.z, ph, pl), dq(w.w, ph, pl));
}

__device__ __forceinline__ f32x4 mfma16(half8 a, half8 b, f32x4 c) {
  return __builtin_amdgcn_mfma_f32_16x16x32_f16(a, b, c, 0, 0, 0);
}

// ---------------------------------------------------------------------------
// Round 12 = round 11 resubmission (+ t-loop unroll cap, compile-size hedge).
// 256x256 tile, BK=64, 8-phase counted-vmcnt schedule (T2+T3+T4+T5).
// 512 threads = 8 waves (2M x 4N), per-wave 128x64 output, acc[8][4] f32x4.
// LDS [2buf][2kh][256][32] fp16 per matrix = 128 KiB total, 1 WG/CU.
// Per K-tile: 4 phases {kh,mhalf}; each phase = ds_read subtile + 1 half-tile
// GLL prefetch + barrier + lgkmcnt(0) + 16 MFMA + barrier.  vmcnt(8) only at
// phases 2 & 4 (4 half-tiles = 8 loads always in flight; never drained).
// Stage queue: ph1->B.k1(t+1), ph2->A.k1(t+1), ph3->B.k0(t+2), ph4->A.k0(t+2);
// (t+2) regions are dead by then (B.k0 dies after ph1, A.k0 after ph2).
// Ledger (verified by walk-through): prologue 6 half-tiles, vmcnt(8) retires
// exactly {B0(0),A0(0)} = phase-1 reads; steady-state vmcnt(8) at ph2/ph4
// retires the half-tiles read one phase later; tail vmcnt(4)/(0).
// XOR chunk swizzle (proven r9): phys chunk = logical ^ ((row>>1)&3), applied
// on the GLL *source* address (dest stays linear, rule 21); reads 2-way = free.
// ---------------------------------------------------------------------------
#define NT (K_DIM / 64)

__global__ __launch_bounds__(512, 2) void f16gemm256_kernel(
    const uint8_t* __restrict__ xh,    // fp16 bits [M, K] (ws + 0)
    const uint8_t* __restrict__ wh,    // fp16 bits [N, K] (ws + 32MB)
    float* __restrict__ out)           // [M, N] float32
{
  __shared__ uint16_t Al[2][2][256 * 32];   // [buf][kh][row][chunk*8+e]
  __shared__ uint16_t Bl[2][2][256 * 32];

  const int tid  = threadIdx.x;
  const int lane = tid & 63;
  const int wave = tid >> 6;           // 0..7
  const int wm   = wave >> 2;          // 0..1  (128-row half of M tile)
  const int wn   = wave & 3;           // 0..3  (64-col quarter of N tile)

  // Bijective XCD swizzle: 256 blocks, 8 XCDs, 32 blocks each -> each XCD's
  // blocks share 2 A-panels (4 MB, L2-fit).
  const int bid = blockIdx.x;
  const int sw  = (bid & 7) * 32 + (bid >> 3);
  const int m0  = (sw >> 4) * 256;
  const int n0  = (sw & 15) * 256;

  // --- staging geometry: slot = tid + s*512 over a 1024-slot (16 KB) region;
  //     phys slot (row, cc) sources global chunk cc ^ ((row>>1)&3).
  const uint8_t* asrc[2];
  const uint8_t* bsrc[2];
  int ldst[2];
#pragma unroll
  for (int s = 0; s < 2; ++s) {
    const int slot = tid + s * 512;
    const int row  = slot >> 2;
    const int g    = (slot & 3) ^ ((row >> 1) & 3);
    asrc[s] = xh + ((size_t)(m0 + row) * K_DIM) * 2 + g * 16;
    bsrc[s] = wh + ((size_t)(n0 + row) * K_DIM) * 2 + g * 16;
    ldst[s] = slot * 16;
  }

  auto STAGE = [&](int isB, int buf, int kh, int tt) {
    const int koff  = tt * 128 + kh * 64;   // global k byte offset
    uint8_t* lb = (uint8_t*)(isB ? &Bl[0][0][0] : &Al[0][0][0]) +
                  (buf * 2 + kh) * 16384;
#pragma unroll
    for (int s = 0; s < 2; ++s) {
      const uint8_t* gp = (isB ? bsrc[s] : asrc[s]) + koff;
      __builtin_amdgcn_global_load_lds(
          (const __attribute__((address_space(1))) uint32_t*)gp,
          (__attribute__((address_space(3))) uint32_t*)(lb + ldst[s]), 16, 0, 0);
    }
  };

  // --- per-thread fragment read offsets (u16 units within a (buf,kh) region)
  int aoff[8], boff[4];
#pragma unroll
  for (int m = 0; m < 8; ++m) {
    const int row = wm * 128 + m * 16 + (lane & 15);
    const int ch  = (lane >> 4) ^ ((row >> 1) & 3);
    aoff[m] = row * 32 + ch * 8;
  }
#pragma unroll
  for (int n = 0; n < 4; ++n) {
    const int row = wn * 64 + n * 16 + (lane & 15);
    const int ch  = (lane >> 4) ^ ((row >> 1) & 3);
    boff[n] = row * 32 + ch * 8;
  }

  f32x4 acc[8][4];
#pragma unroll
  for (int i = 0; i < 8; ++i)
#pragma unroll
    for (int j = 0; j < 4; ++j) acc[i][j] = (f32x4){0.f, 0.f, 0.f, 0.f};

  // --- prologue: queue [B0(0),A0(0),B1(0),A1(0),B0(1),A0(1)]; vmcnt(8)
  //     retires exactly the 4 oldest loads = {B0(0),A0(0)} (phase-1 reads).
  STAGE(1, 0, 0, 0);
  STAGE(0, 0, 0, 0);
  STAGE(1, 0, 1, 0);
  STAGE(0, 0, 1, 0);
  STAGE(1, 1, 0, 1);
  STAGE(0, 1, 0, 1);
  asm volatile("s_waitcnt vmcnt(8)" ::: "memory");
  __builtin_amdgcn_s_barrier();

  half8 af[4], bfr[4];

#pragma unroll 2
  for (int t = 0; t < NT; ++t) {
    const int cur = t & 1;
    const uint16_t* Ab = &Al[cur][0][0];
    const uint16_t* Bb = &Bl[cur][0][0];
    const bool st1 = (t + 1 < NT);
    const bool st2 = (t + 2 < NT);

    // ===== phase 1: kh=0, M-frags 0-3 =====
#pragma unroll
    for (int n = 0; n < 4; ++n) bfr[n] = *(const half8*)(Bb + boff[n]);
#pragma unroll
    for (int m = 0; m < 4; ++m) af[m] = *(const half8*)(Ab + aoff[m]);
    if (st1) STAGE(1, cur ^ 1, 1, t + 1);
    __builtin_amdgcn_s_barrier();
    asm volatile("s_waitcnt lgkmcnt(0)" ::: "memory");
    __builtin_amdgcn_sched_barrier(0);
    __builtin_amdgcn_s_setprio(1);
#pragma unroll
    for (int m = 0; m < 4; ++m)
#pragma unroll
      for (int n = 0; n < 4; ++n)
        acc[m][n] = mfma16(af[m], bfr[n], acc[m][n]);
    __builtin_amdgcn_s_setprio(0);
    __builtin_amdgcn_s_barrier();

    // ===== phase 2: kh=0, M-frags 4-7 =====
#pragma unroll
    for (int m = 0; m < 4; ++m) af[m] = *(const half8*)(Ab + aoff[4 + m]);
    if (st1) STAGE(0, cur ^ 1, 1, t + 1);
    __builtin_amdgcn_s_barrier();
    asm volatile("s_waitcnt lgkmcnt(0)" ::: "memory");
    __builtin_amdgcn_sched_barrier(0);
    __builtin_amdgcn_s_setprio(1);
#pragma unroll
    for (int m = 0; m < 4; ++m)
#pragma unroll
      for (int n = 0; n < 4; ++n)
        acc[4 + m][n] = mfma16(af[m], bfr[n], acc[4 + m][n]);
    __builtin_amdgcn_s_setprio(0);
    if (st1) asm volatile("s_waitcnt vmcnt(8)" ::: "memory");
    else     asm volatile("s_waitcnt vmcnt(0)" ::: "memory");
    __builtin_amdgcn_s_barrier();

    // ===== phase 3: kh=1, M-frags 0-3 =====
#pragma unroll
    for (int n = 0; n < 4; ++n) bfr[n] = *(const half8*)(Bb + 8192 + boff[n]);
#pragma unroll
    for (int m = 0; m < 4; ++m) af[m] = *(const half8*)(Ab + 8192 + aoff[m]);
    if (st2) STAGE(1, cur, 0, t + 2);
    __builtin_amdgcn_s_barrier();
    asm volatile("s_waitcnt lgkmcnt(0)" ::: "memory");
    __builtin_amdgcn_sched_barrier(0);
    __builtin_amdgcn_s_setprio(1);
#pragma unroll
    for (int m = 0; m < 4; ++m)
#pragma unroll
      for (int n = 0; n < 4; ++n)
        acc[m][n] = mfma16(af[m], bfr[n], acc[m][n]);
    __builtin_amdgcn_s_setprio(0);
    __builtin_amdgcn_s_barrier();

    // ===== phase 4: kh=1, M-frags 4-7 =====
#pragma unroll
    for (int m = 0; m < 4; ++m) af[m] = *(const half8*)(Ab + 8192 + aoff[4 + m]);
    if (st2) STAGE(0, cur, 0, t + 2);
    __builtin_amdgcn_s_barrier();
    asm volatile("s_waitcnt lgkmcnt(0)" ::: "memory");
    __builtin_amdgcn_sched_barrier(0);
    __builtin_amdgcn_s_setprio(1);
#pragma unroll
    for (int m = 0; m < 4; ++m)
#pragma unroll
      for (int n = 0; n < 4; ++n)
        acc[4 + m][n] = mfma16(af[m], bfr[n], acc[4 + m][n]);
    __builtin_amdgcn_s_setprio(0);
    if (st2)      asm volatile("s_waitcnt vmcnt(8)" ::: "memory");
    else if (st1) asm volatile("s_waitcnt vmcnt(4)" ::: "memory");
    __builtin_amdgcn_s_barrier();
  }

  // ---- Epilogue: C/D layout col(n) = lane&15, row(m) = (lane>>4)*4 + r ----
  const int mb = m0 + wm * 128 + (lane >> 4) * 4;
  const int nb = n0 + wn * 64 + (lane & 15);
#pragma unroll
  for (int m = 0; m < 8; ++m)
#pragma unroll
    for (int n = 0; n < 4; ++n)
#pragma unroll
      for (int r = 0; r < 4; ++r)
        out[(size_t)(mb + m * 16 + r) * N_DIM + (nb + n * 16)] = acc[m][n][r];
}

// ---------------------------------------------------------------------------
// Fallback (r9 champion): 128x128, in-loop B dequant — used only if d_ws is
// too small for both fp16 operands.
// ---------------------------------------------------------------------------
#define BM 128
#define BN 128
#define BK 32

__global__ __launch_bounds__(256, 2) void fp4gemm_kernel(
    const uint8_t* __restrict__ xh, const int* __restrict__ pw,
    const float* __restrict__ lutf, float* __restrict__ out)
{
  __shared__ uint16_t ldsA[BM * BK];
  __shared__ uint16_t ldsB[BN * BK];

  const int tid  = threadIdx.x;
  const int lane = tid & 63;
  const int wave = tid >> 6;
  const int wm   = wave >> 1;
  const int wn   = wave & 1;
  const int m0 = blockIdx.y * BM;
  const int n0 = blockIdx.x * BN;

  uint32_t ph, pl;
  lut_pool(lutf, ph, pl);

  f32x4 acc[4][4];
#pragma unroll
  for (int i = 0; i < 4; ++i)
#pragma unroll
    for (int j = 0; j < 4; ++j) acc[i][j] = (f32x4){0.f, 0.f, 0.f, 0.f};

  const int rowB  = tid >> 1;
  const int halfB = tid & 1;
  const int swzB  = (rowB >> 1) & 3;

  for (int kt = 0; kt < K_DIM / BK; ++kt) {
    __syncthreads();

#pragma unroll
    for (int s = 0; s < 2; ++s) {
      const int idx = tid + s * 256;
      const int row = idx >> 2;
      const int c16 = idx & 3;
      const int g16 = c16 ^ ((row >> 1) & 3);
      const uint8_t* gp = xh + ((size_t)(m0 + row) * K_DIM + kt * BK) * 2 + g16 * 16;
      uint8_t* lp = (uint8_t*)ldsA + (size_t)idx * 16;
      __builtin_amdgcn_global_load_lds(
          (const __attribute__((address_space(1))) uint32_t*)gp,
          (__attribute__((address_space(3))) uint32_t*)lp, 16, 0, 0);
    }

    {
      const int* gp = pw + (size_t)(n0 + rowB) * KW + kt * (BK / 2) + halfB * 8;
      const int4 wA = ((const int4*)gp)[0];
      const int4 wB = ((const int4*)gp)[1];
      uint8_t* base = (uint8_t*)ldsB + rowB * 64;
      *(uint4*)(base + ((halfB * 2 + 0) ^ swzB) * 16) =
          make_uint4(dq(wA.x, ph, pl), dq(wA.y, ph, pl),
                     dq(wA.z, ph, pl), dq(wA.w, ph, pl));
      *(uint4*)(base + ((halfB * 2 + 1) ^ swzB) * 16) =
          make_uint4(dq(wB.x, ph, pl), dq(wB.y, ph, pl),
                     dq(wB.z, ph, pl), dq(wB.w, ph, pl));
    }

    __syncthreads();

    const int q = lane >> 4;
    half8 af[4], bfr[4];
#pragma unroll
    for (int i = 0; i < 4; ++i) {
      const int row = wm * 64 + i * 16 + (lane & 15);
      af[i] = *(const half8*)(ldsA + row * BK + (q ^ ((row >> 1) & 3)) * 8);
    }
#pragma unroll
    for (int j = 0; j < 4; ++j) {
      const int row = wn * 64 + j * 16 + (lane & 15);
      bfr[j] = *(const half8*)(ldsB + row * BK + (q ^ ((row >> 1) & 3)) * 8);
    }
#pragma unroll
    for (int i = 0; i < 4; ++i)
#pragma unroll
      for (int j = 0; j < 4; ++j)
        acc[i][j] = __builtin_amdgcn_mfma_f32_16x16x32_f16(af[i], bfr[j], acc[i][j], 0, 0, 0);
  }

  const int mb = m0 + wm * 64 + (lane >> 4) * 4;
  const int nb = n0 + wn * 64 + (lane & 15);
#pragma unroll
  for (int i = 0; i < 4; ++i)
#pragma unroll
    for (int j = 0; j < 4; ++j)
#pragma unroll
      for (int r = 0; r < 4; ++r)
        out[(size_t)(mb + i * 16 + r) * N_DIM + (nb + j * 16)] = acc[i][j][r];
}

extern "C" void kernel_launch(void* const* d_in, const int* in_sizes, int n_in,
                              void* d_out, int out_size, void* d_ws, size_t ws_size,
                              hipStream_t stream) {
  // Size-based dispatch (element counts are dtype-independent and unique).
  const void* px = nullptr; const void* ppw = nullptr; const void* plut = nullptr;
  for (int i = 0; i < n_in; ++i) {
    const long s = in_sizes[i];
    if (s == (long)M_DIM * K_DIM) px = d_in[i];
    else if (s == (long)N_DIM * KW) ppw = d_in[i];
    else if (s == 16) plut = d_in[i];
  }
  if (!px || !ppw || !plut) { px = d_in[0]; ppw = d_in[1]; plut = d_in[2]; }

  // x f32 -> fp16 into ws[0, 32MB).
  cvt_x_kernel<<<(M_DIM * K_DIM / 8) / 256, 256, 0, stream>>>(
      (const float4*)px, (uint4*)d_ws);

  if (ws_size >= WS_XH_BYTES + WS_WH_BYTES) {
    // W fp4 -> fp16 into ws[32MB, 64MB), then 256^2 8-phase f16 GEMM.
    uint8_t* wh = (uint8_t*)d_ws + WS_XH_BYTES;
    wdq_kernel<<<(N_DIM * KW / 4) / 256, 256, 0, stream>>>(
        (const int4*)ppw, (uint4*)wh, (const float*)plut);
    f16gemm256_kernel<<<dim3(256), dim3(512), 0, stream>>>(
        (const uint8_t*)d_ws, wh, (float*)d_out);
  } else {
    dim3 grid(N_DIM / BN, M_DIM / BM);
    fp4gemm_kernel<<<grid, dim3(256), 0, stream>>>(
        (const uint8_t*)d_ws, (const int*)ppw, (const float*)plut, (float*)d_out);
  }
}

// Round 4
// 265.651 us; speedup vs baseline: 1.1226x; 1.0122x over previous
//
#include <hip/hip_runtime.h>
#include <hip/hip_fp16.h>
#include <stdint.h>

// Problem constants (fixed: M=N=K=4096).
// Harness buffer reality (proven r5-r8): x,lut,out are float32; packed_weight
// is int32 holding ONE byte per element (hi nibble = even k, lo nibble = odd k).
#define M_DIM 4096
#define N_DIM 4096
#define K_DIM 4096
#define KW (K_DIM / 2)
#define WS_XH_BYTES ((size_t)M_DIM * K_DIM * 2)  // 32 MB: x as fp16
#define WS_WH_BYTES ((size_t)N_DIM * K_DIM * 2)  // 32 MB: W as fp16

typedef _Float16 half8 __attribute__((ext_vector_type(8)));   // 4 VGPRs (MFMA A/B)
typedef float f32x4 __attribute__((ext_vector_type(4)));      // MFMA accumulator

__device__ __forceinline__ uint32_t pk2(float a, float b) {
  // packed f32->f16 RTZ (exact: every input value is fp16-representable)
  auto h = __builtin_amdgcn_cvt_pkrtz(a, b);  // a -> low halfword
  return __builtin_bit_cast(uint32_t, h);
}

// Dequant one packed byte -> u32 (fp16 even-k | fp16 odd-k << 16) via v_perm
// byte lookup in an 8-byte magnitude pool. [proven bit-exact r6-r8]
__device__ __forceinline__ uint32_t dq(uint32_t b, uint32_t ph, uint32_t pl) {
#if __has_builtin(__builtin_amdgcn_perm)
  const uint32_t sel = ((b & 0x70u) << 4) | ((b & 0x07u) << 24);
  uint32_t v = __builtin_amdgcn_perm(ph, pl, sel);  // bytes 4-7 = ph, 0-3 = pl
#else
  const uint64_t pool = ((uint64_t)ph << 32) | pl;
  const uint32_t mh = (uint32_t)(pool >> (((b >> 4) & 7u) * 8)) & 0xFFu;
  const uint32_t ml = (uint32_t)(pool >> ((b & 7u) * 8)) & 0xFFu;
  uint32_t v = (mh << 8) | (ml << 24);
#endif
  const uint32_t sg = ((b & 0x88u) * 0x10000100u) & 0x80008000u;  // b7->15, b3->31
  return v | sg;
}

__device__ __forceinline__ void lut_pool(const float* __restrict__ lutf,
                                         uint32_t& ph, uint32_t& pl) {
  const uint32_t h01 = pk2(lutf[0], lutf[1]);
  const uint32_t h23 = pk2(lutf[2], lutf[3]);
  const uint32_t h45 = pk2(lutf[4], lutf[5]);
  const uint32_t h67 = pk2(lutf[6], lutf[7]);
#if __has_builtin(__builtin_amdgcn_perm)
  pl = __builtin_amdgcn_perm(h23, h01, 0x07050301u);
  ph = __builtin_amdgcn_perm(h67, h45, 0x07050301u);
#else
  pl = ((h01 >> 8) & 0xFFu) | ((h01 >> 24) << 8) |
       (((h23 >> 8) & 0xFFu) << 16) | ((h23 >> 24) << 24);
  ph = ((h45 >> 8) & 0xFFu) | ((h45 >> 24) << 8) |
       (((h67 >> 8) & 0xFFu) << 16) | ((h67 >> 24) << 24);
#endif
}

// Fused pre-pass (r13): blocks [0,8192) convert x f32->f16; blocks [8192,16384)
// dequant W packed->f16. One launch, both streams concurrent; 160 MB traffic.
#define XBLOCKS (M_DIM * K_DIM / 8 / 256)   // 8192
#define WBLOCKS (N_DIM * KW / 4 / 256)      // 8192

__global__ __launch_bounds__(256) void prep_kernel(
    const float4* __restrict__ xin, uint4* __restrict__ xout,
    const int4* __restrict__ pin, uint4* __restrict__ wout,
    const float* __restrict__ lutf) {
  const int b = blockIdx.x;
  if (b < XBLOCKS) {
    const int i = b * 256 + threadIdx.x;   // uint4 index
    const float4 v0 = xin[2 * i];
    const float4 v1 = xin[2 * i + 1];
    xout[i] = make_uint4(pk2(v0.x, v0.y), pk2(v0.z, v0.w),
                         pk2(v1.x, v1.y), pk2(v1.z, v1.w));
  } else {
    uint32_t ph, pl;
    lut_pool(lutf, ph, pl);
    const int i = (b - XBLOCKS) * 256 + threadIdx.x;  // int4 index
    const int4 w = pin[i];
    wout[i] = make_uint4(dq(w.x, ph, pl), dq(w.y, ph, pl),
                         dq(w.z, ph, pl), dq(w.w, ph, pl));
  }
}

// Pre-pass (fallback path only): x f32 -> fp16.
__global__ __launch_bounds__(256) void cvt_x_kernel(const float4* __restrict__ xin,
                                                    uint4* __restrict__ xout) {
  const int i = blockIdx.x * 256 + threadIdx.x;
  const float4 v0 = xin[2 * i];
  const float4 v1 = xin[2 * i + 1];
  xout[i] = make_uint4(pk2(v0.x, v0.y), pk2(v0.z, v0.w),
                       pk2(v1.x, v1.y), pk2(v1.z, v1.w));
}

__device__ __forceinline__ f32x4 mfma16(half8 a, half8 b, f32x4 c) {
  return __builtin_amdgcn_mfma_f32_16x16x32_f16(a, b, c, 0, 0, 0);
}

// ---------------------------------------------------------------------------
// Round 13: merged-phase 256x256 schedule (2 phases/K-tile, 32-MFMA clusters),
// compiler-scheduled fine lgkmcnt (forced lgkmcnt(0)+sched_barrier REMOVED —
// r3 PMC showed they fully serialized the LDS-read and MFMA periods:
// 1318 cy/phase ~= 621 MFMA + 700 read, zero overlap).
// 512 threads = 8 waves (2M x 4N), per-wave 128x64 output, acc[8][4] f32x4.
// LDS [2buf][2kh][256][32] fp16 per matrix = 128 KiB, 1 WG/CU.
// Ledger (re-derived r13, walked steady-state + tail):
//   prologue: stage B0(0),A0(0),B1(0),A1(0),B0(1),A0(1); vmcnt(8) retires
//             {B0(0),A0(0)} = alpha(0) reads; barrier publishes.
//   alpha(t): reads B/A[cur][k0] (12 b128); stages B.k1,A.k1(t+1) -> cur^1;
//             bar; 32 MFMA; vmcnt(8) retires {B1(t),A1(t)} = beta(t) reads; bar.
//   beta(t):  reads B/A[cur][k1]; stages B.k0,A.k0(t+2) -> cur;
//             bar; 32 MFMA; vmcnt(8) retires {B0(t+1),A0(t+1)}; bar.
//   tail: alpha(63) vmcnt(0); beta(62) vmcnt(4); beta(63) no wait.
// WAR: stage(alpha(t)) overwrites regions last read in beta(t-1); separated by
// beta(t-1)'s post-MFMA vmcnt+barrier (reads retire before barrier arrival).
// XOR chunk swizzle (proven r9): phys chunk = logical ^ ((row>>1)&3) on the
// GLL *source* address (dest linear, rule 21); frag reads 2-way/bank = free.
// ---------------------------------------------------------------------------
#define NT (K_DIM / 64)

__global__ __launch_bounds__(512, 2) void f16gemm256_kernel(
    const uint8_t* __restrict__ xh,    // fp16 bits [M, K] (ws + 0)
    const uint8_t* __restrict__ wh,    // fp16 bits [N, K] (ws + 32MB)
    float* __restrict__ out)           // [M, N] float32
{
  __shared__ uint16_t Al[2][2][256 * 32];   // [buf][kh][row][chunk*8+e]
  __shared__ uint16_t Bl[2][2][256 * 32];

  const int tid  = threadIdx.x;
  const int lane = tid & 63;
  const int wave = tid >> 6;           // 0..7
  const int wm   = wave >> 2;          // 0..1  (128-row half of M tile)
  const int wn   = wave & 3;           // 0..3  (64-col quarter of N tile)

  // Bijective XCD swizzle: 256 blocks, 8 XCDs, 32 blocks each.
  const int bid = blockIdx.x;
  const int sw  = (bid & 7) * 32 + (bid >> 3);
  const int m0  = (sw >> 4) * 256;
  const int n0  = (sw & 15) * 256;

  // Staging geometry: slot = tid + s*512 over a 1024-slot (16 KB) region;
  // phys slot (row, cc) sources global chunk cc ^ ((row>>1)&3).
  const uint8_t* asrc[2];
  const uint8_t* bsrc[2];
  int ldst[2];
#pragma unroll
  for (int s = 0; s < 2; ++s) {
    const int slot = tid + s * 512;
    const int row  = slot >> 2;
    const int g    = (slot & 3) ^ ((row >> 1) & 3);
    asrc[s] = xh + ((size_t)(m0 + row) * K_DIM) * 2 + g * 16;
    bsrc[s] = wh + ((size_t)(n0 + row) * K_DIM) * 2 + g * 16;
    ldst[s] = slot * 16;
  }

  auto STAGE = [&](int isB, int buf, int kh, int tt) {
    const int koff  = tt * 128 + kh * 64;   // global k byte offset
    uint8_t* lb = (uint8_t*)(isB ? &Bl[0][0][0] : &Al[0][0][0]) +
                  (buf * 2 + kh) * 16384;
#pragma unroll
    for (int s = 0; s < 2; ++s) {
      const uint8_t* gp = (isB ? bsrc[s] : asrc[s]) + koff;
      __builtin_amdgcn_global_load_lds(
          (const __attribute__((address_space(1))) uint32_t*)gp,
          (__attribute__((address_space(3))) uint32_t*)(lb + ldst[s]), 16, 0, 0);
    }
  };

  // Per-thread fragment read offsets (u16 units within a (buf,kh) region).
  int aoff[8], boff[4];
#pragma unroll
  for (int m = 0; m < 8; ++m) {
    const int row = wm * 128 + m * 16 + (lane & 15);
    const int ch  = (lane >> 4) ^ ((row >> 1) & 3);
    aoff[m] = row * 32 + ch * 8;
  }
#pragma unroll
  for (int n = 0; n < 4; ++n) {
    const int row = wn * 64 + n * 16 + (lane & 15);
    const int ch  = (lane >> 4) ^ ((row >> 1) & 3);
    boff[n] = row * 32 + ch * 8;
  }

  f32x4 acc[8][4];
#pragma unroll
  for (int i = 0; i < 8; ++i)
#pragma unroll
    for (int j = 0; j < 4; ++j) acc[i][j] = (f32x4){0.f, 0.f, 0.f, 0.f};

  // Prologue: queue 6 half-tiles; vmcnt(8) retires {B0(0),A0(0)}.
  STAGE(1, 0, 0, 0);
  STAGE(0, 0, 0, 0);
  STAGE(1, 0, 1, 0);
  STAGE(0, 0, 1, 0);
  STAGE(1, 1, 0, 1);
  STAGE(0, 1, 0, 1);
  asm volatile("s_waitcnt vmcnt(8)" ::: "memory");
  __builtin_amdgcn_s_barrier();

  half8 af[8], bfr[4];

#pragma unroll 2
  for (int t = 0; t < NT; ++t) {
    const int cur = t & 1;
    const uint16_t* Ab = &Al[cur][0][0];
    const uint16_t* Bb = &Bl[cur][0][0];
    const bool st1 = (t + 1 < NT);
    const bool st2 = (t + 2 < NT);

    // ===== phase alpha: kh=0, all 8 M-frags, 32 MFMA =====
#pragma unroll
    for (int n = 0; n < 4; ++n) bfr[n] = *(const half8*)(Bb + boff[n]);
#pragma unroll
    for (int m = 0; m < 8; ++m) af[m] = *(const half8*)(Ab + aoff[m]);
    if (st1) { STAGE(1, cur ^ 1, 1, t + 1); STAGE(0, cur ^ 1, 1, t + 1); }
    __builtin_amdgcn_s_barrier();
    // no forced lgkm drain: compiler interleaves staged lgkmcnt(N) with MFMAs
    __builtin_amdgcn_s_setprio(1);
#pragma unroll
    for (int m = 0; m < 8; ++m)
#pragma unroll
      for (int n = 0; n < 4; ++n)
        acc[m][n] = mfma16(af[m], bfr[n], acc[m][n]);
    __builtin_amdgcn_s_setprio(0);
    if (st1) asm volatile("s_waitcnt vmcnt(8)" ::: "memory");
    else     asm volatile("s_waitcnt vmcnt(0)" ::: "memory");
    __builtin_amdgcn_s_barrier();

    // ===== phase beta: kh=1, all 8 M-frags, 32 MFMA =====
#pragma unroll
    for (int n = 0; n < 4; ++n) bfr[n] = *(const half8*)(Bb + 8192 + boff[n]);
#pragma unroll
    for (int m = 0; m < 8; ++m) af[m] = *(const half8*)(Ab + 8192 + aoff[m]);
    if (st2) { STAGE(1, cur, 0, t + 2); STAGE(0, cur, 0, t + 2); }
    __builtin_amdgcn_s_barrier();
    __builtin_amdgcn_s_setprio(1);
#pragma unroll
    for (int m = 0; m < 8; ++m)
#pragma unroll
      for (int n = 0; n < 4; ++n)
        acc[m][n] = mfma16(af[m], bfr[n], acc[m][n]);
    __builtin_amdgcn_s_setprio(0);
    if (st2)      asm volatile("s_waitcnt vmcnt(8)" ::: "memory");
    else if (st1) asm volatile("s_waitcnt vmcnt(4)" ::: "memory");
    __builtin_amdgcn_s_barrier();
  }

  // ---- Epilogue: C/D layout col(n) = lane&15, row(m) = (lane>>4)*4 + r ----
  const int mb = m0 + wm * 128 + (lane >> 4) * 4;
  const int nb = n0 + wn * 64 + (lane & 15);
#pragma unroll
  for (int m = 0; m < 8; ++m)
#pragma unroll
    for (int n = 0; n < 4; ++n)
#pragma unroll
      for (int r = 0; r < 4; ++r)
        out[(size_t)(mb + m * 16 + r) * N_DIM + (nb + n * 16)] = acc[m][n][r];
}

// ---------------------------------------------------------------------------
// Fallback (r9 champion): 128x128, in-loop B dequant — used only if d_ws is
// too small for both fp16 operands.
// ---------------------------------------------------------------------------
#define BM 128
#define BN 128
#define BK 32

__global__ __launch_bounds__(256, 2) void fp4gemm_kernel(
    const uint8_t* __restrict__ xh, const int* __restrict__ pw,
    const float* __restrict__ lutf, float* __restrict__ out)
{
  __shared__ uint16_t ldsA[BM * BK];
  __shared__ uint16_t ldsB[BN * BK];

  const int tid  = threadIdx.x;
  const int lane = tid & 63;
  const int wave = tid >> 6;
  const int wm   = wave >> 1;
  const int wn   = wave & 1;
  const int m0 = blockIdx.y * BM;
  const int n0 = blockIdx.x * BN;

  uint32_t ph, pl;
  lut_pool(lutf, ph, pl);

  f32x4 acc[4][4];
#pragma unroll
  for (int i = 0; i < 4; ++i)
#pragma unroll
    for (int j = 0; j < 4; ++j) acc[i][j] = (f32x4){0.f, 0.f, 0.f, 0.f};

  const int rowB  = tid >> 1;
  const int halfB = tid & 1;
  const int swzB  = (rowB >> 1) & 3;

  for (int kt = 0; kt < K_DIM / BK; ++kt) {
    __syncthreads();

#pragma unroll
    for (int s = 0; s < 2; ++s) {
      const int idx = tid + s * 256;
      const int row = idx >> 2;
      const int c16 = idx & 3;
      const int g16 = c16 ^ ((row >> 1) & 3);
      const uint8_t* gp = xh + ((size_t)(m0 + row) * K_DIM + kt * BK) * 2 + g16 * 16;
      uint8_t* lp = (uint8_t*)ldsA + (size_t)idx * 16;
      __builtin_amdgcn_global_load_lds(
          (const __attribute__((address_space(1))) uint32_t*)gp,
          (__attribute__((address_space(3))) uint32_t*)lp, 16, 0, 0);
    }

    {
      const int* gp = pw + (size_t)(n0 + rowB) * KW + kt * (BK / 2) + halfB * 8;
      const int4 wA = ((const int4*)gp)[0];
      const int4 wB = ((const int4*)gp)[1];
      uint8_t* base = (uint8_t*)ldsB + rowB * 64;
      *(uint4*)(base + ((halfB * 2 + 0) ^ swzB) * 16) =
          make_uint4(dq(wA.x, ph, pl), dq(wA.y, ph, pl),
                     dq(wA.z, ph, pl), dq(wA.w, ph, pl));
      *(uint4*)(base + ((halfB * 2 + 1) ^ swzB) * 16) =
          make_uint4(dq(wB.x, ph, pl), dq(wB.y, ph, pl),
                     dq(wB.z, ph, pl), dq(wB.w, ph, pl));
    }

    __syncthreads();

    const int q = lane >> 4;
    half8 af[4], bfr[4];
#pragma unroll
    for (int i = 0; i < 4; ++i) {
      const int row = wm * 64 + i * 16 + (lane & 15);
      af[i] = *(const half8*)(ldsA + row * BK + (q ^ ((row >> 1) & 3)) * 8);
    }
#pragma unroll
    for (int j = 0; j < 4; ++j) {
      const int row = wn * 64 + j * 16 + (lane & 15);
      bfr[j] = *(const half8*)(ldsB + row * BK + (q ^ ((row >> 1) & 3)) * 8);
    }
#pragma unroll
    for (int i = 0; i < 4; ++i)
#pragma unroll
      for (int j = 0; j < 4; ++j)
        acc[i][j] = __builtin_amdgcn_mfma_f32_16x16x32_f16(af[i], bfr[j], acc[i][j], 0, 0, 0);
  }

  const int mb = m0 + wm * 64 + (lane >> 4) * 4;
  const int nb = n0 + wn * 64 + (lane & 15);
#pragma unroll
  for (int i = 0; i < 4; ++i)
#pragma unroll
    for (int j = 0; j < 4; ++j)
#pragma unroll
      for (int r = 0; r < 4; ++r)
        out[(size_t)(mb + i * 16 + r) * N_DIM + (nb + j * 16)] = acc[i][j][r];
}

extern "C" void kernel_launch(void* const* d_in, const int* in_sizes, int n_in,
                              void* d_out, int out_size, void* d_ws, size_t ws_size,
                              hipStream_t stream) {
  // Size-based dispatch (element counts are dtype-independent and unique).
  const void* px = nullptr; const void* ppw = nullptr; const void* plut = nullptr;
  for (int i = 0; i < n_in; ++i) {
    const long s = in_sizes[i];
    if (s == (long)M_DIM * K_DIM) px = d_in[i];
    else if (s == (long)N_DIM * KW) ppw = d_in[i];
    else if (s == 16) plut = d_in[i];
  }
  if (!px || !ppw || !plut) { px = d_in[0]; ppw = d_in[1]; plut = d_in[2]; }

  if (ws_size >= WS_XH_BYTES + WS_WH_BYTES) {
    // Fused prep: x f32->f16 into ws[0,32MB) and W fp4->f16 into ws[32MB,64MB).
    uint8_t* wh = (uint8_t*)d_ws + WS_XH_BYTES;
    prep_kernel<<<XBLOCKS + WBLOCKS, 256, 0, stream>>>(
        (const float4*)px, (uint4*)d_ws, (const int4*)ppw, (uint4*)wh,
        (const float*)plut);
    f16gemm256_kernel<<<dim3(256), dim3(512), 0, stream>>>(
        (const uint8_t*)d_ws, wh, (float*)d_out);
  } else {
    cvt_x_kernel<<<(M_DIM * K_DIM / 8) / 256, 256, 0, stream>>>(
        (const float4*)px, (uint4*)d_ws);
    dim3 grid(N_DIM / BN, M_DIM / BM);
    fp4gemm_kernel<<<grid, dim3(256), 0, stream>>>(
        (const uint8_t*)d_ws, (const int*)ppw, (const float*)plut, (float*)d_out);
  }
}

// Round 5
// 253.988 us; speedup vs baseline: 1.1742x; 1.0459x over previous
//
#include <hip/hip_runtime.h>
#include <hip/hip_fp16.h>
#include <stdint.h>

// Problem constants (fixed: M=N=K=4096).
// Harness buffer reality (proven r5-r8): x,lut,out are float32; packed_weight
// is int32 holding ONE byte per element (hi nibble = even k, lo nibble = odd k).
#define M_DIM 4096
#define N_DIM 4096
#define K_DIM 4096
#define KW (K_DIM / 2)
#define WS_XH_BYTES ((size_t)M_DIM * K_DIM * 2)  // 32 MB: x as fp16
#define WS_WH_BYTES ((size_t)N_DIM * K_DIM * 2)  // 32 MB: W as fp16

typedef _Float16 half8 __attribute__((ext_vector_type(8)));   // 4 VGPRs (MFMA A/B)
typedef float f32x4 __attribute__((ext_vector_type(4)));      // MFMA accumulator

__device__ __forceinline__ uint32_t pk2(float a, float b) {
  // packed f32->f16 RTZ (exact: every input value is fp16-representable)
  auto h = __builtin_amdgcn_cvt_pkrtz(a, b);  // a -> low halfword
  return __builtin_bit_cast(uint32_t, h);
}

// Dequant one packed byte -> u32 (fp16 even-k | fp16 odd-k << 16) via v_perm
// byte lookup in an 8-byte magnitude pool. [proven bit-exact r6-r8]
__device__ __forceinline__ uint32_t dq(uint32_t b, uint32_t ph, uint32_t pl) {
#if __has_builtin(__builtin_amdgcn_perm)
  const uint32_t sel = ((b & 0x70u) << 4) | ((b & 0x07u) << 24);
  uint32_t v = __builtin_amdgcn_perm(ph, pl, sel);  // bytes 4-7 = ph, 0-3 = pl
#else
  const uint64_t pool = ((uint64_t)ph << 32) | pl;
  const uint32_t mh = (uint32_t)(pool >> (((b >> 4) & 7u) * 8)) & 0xFFu;
  const uint32_t ml = (uint32_t)(pool >> ((b & 7u) * 8)) & 0xFFu;
  uint32_t v = (mh << 8) | (ml << 24);
#endif
  const uint32_t sg = ((b & 0x88u) * 0x10000100u) & 0x80008000u;  // b7->15, b3->31
  return v | sg;
}

__device__ __forceinline__ void lut_pool(const float* __restrict__ lutf,
                                         uint32_t& ph, uint32_t& pl) {
  const uint32_t h01 = pk2(lutf[0], lutf[1]);
  const uint32_t h23 = pk2(lutf[2], lutf[3]);
  const uint32_t h45 = pk2(lutf[4], lutf[5]);
  const uint32_t h67 = pk2(lutf[6], lutf[7]);
#if __has_builtin(__builtin_amdgcn_perm)
  pl = __builtin_amdgcn_perm(h23, h01, 0x07050301u);
  ph = __builtin_amdgcn_perm(h67, h45, 0x07050301u);
#else
  pl = ((h01 >> 8) & 0xFFu) | ((h01 >> 24) << 8) |
       (((h23 >> 8) & 0xFFu) << 16) | ((h23 >> 24) << 24);
  ph = ((h45 >> 8) & 0xFFu) | ((h45 >> 24) << 8) |
       (((h67 >> 8) & 0xFFu) << 16) | ((h67 >> 24) << 24);
#endif
}

// Fused pre-pass (r13): blocks [0,8192) convert x f32->f16; blocks [8192,16384)
// dequant W packed->f16. One launch, both streams concurrent; 160 MB traffic.
#define XBLOCKS (M_DIM * K_DIM / 8 / 256)   // 8192
#define WBLOCKS (N_DIM * KW / 4 / 256)      // 8192

__global__ __launch_bounds__(256) void prep_kernel(
    const float4* __restrict__ xin, uint4* __restrict__ xout,
    const int4* __restrict__ pin, uint4* __restrict__ wout,
    const float* __restrict__ lutf) {
  const int b = blockIdx.x;
  if (b < XBLOCKS) {
    const int i = b * 256 + threadIdx.x;   // uint4 index
    const float4 v0 = xin[2 * i];
    const float4 v1 = xin[2 * i + 1];
    xout[i] = make_uint4(pk2(v0.x, v0.y), pk2(v0.z, v0.w),
                         pk2(v1.x, v1.y), pk2(v1.z, v1.w));
  } else {
    uint32_t ph, pl;
    lut_pool(lutf, ph, pl);
    const int i = (b - XBLOCKS) * 256 + threadIdx.x;  // int4 index
    const int4 w = pin[i];
    wout[i] = make_uint4(dq(w.x, ph, pl), dq(w.y, ph, pl),
                         dq(w.z, ph, pl), dq(w.w, ph, pl));
  }
}

// Pre-pass (fallback path only): x f32 -> fp16.
__global__ __launch_bounds__(256) void cvt_x_kernel(const float4* __restrict__ xin,
                                                    uint4* __restrict__ xout) {
  const int i = blockIdx.x * 256 + threadIdx.x;
  const float4 v0 = xin[2 * i];
  const float4 v1 = xin[2 * i + 1];
  xout[i] = make_uint4(pk2(v0.x, v0.y), pk2(v0.z, v0.w),
                       pk2(v1.x, v1.y), pk2(v1.z, v1.w));
}

__device__ __forceinline__ f32x4 mfma16(half8 a, half8 b, f32x4 c) {
  return __builtin_amdgcn_mfma_f32_16x16x32_f16(a, b, c, 0, 0, 0);
}

// ---------------------------------------------------------------------------
// Round 14: single-barrier phases. r4 PMC proved the mid-phase s_barrier
// serialized the LDS and MFMA pipes (2637 cy/phase ~= 1242 MFMA + 1152 read,
// zero overlap): the compiler cannot interleave ds_reads with MFMAs across a
// barrier, and the barrier phase-locks all 8 waves into read-burst/MFMA-burst
// lockstep. Hazard audit (r14): that barrier protects nothing — publication
// of a phase's read regions is the END-of-previous-phase vmcnt+barrier; WAR
// for STAGE is covered because prior-phase MFMAs consume the reads (lgkm
// retires pre-MFMA) before the end-of-phase barrier.  New phase shape:
//   { setprio(1); 12 ds_read_b128; STAGE 2 half-tiles; 32 MFMA with
//     compiler-staged lgkm interleave; setprio(0); vmcnt(8); s_barrier }
// Ledger unchanged from r13 (same STAGE order/counts, walked steady+tail):
//   prologue stages 6 half-tiles, vmcnt(8) retires {B0(0),A0(0)}.
//   alpha(t): reads [cur][k0]; stages B1,A1(t+1)->cur^1; vmcnt(8) retires
//             {B1(t),A1(t)} = beta(t) reads; barrier publishes.
//   beta(t):  reads [cur][k1]; stages B0,A0(t+2)->cur;  vmcnt(8) retires
//             {B0(t+1),A0(t+1)}; barrier.  Tail: vmcnt(0)@a63, vmcnt(4)@b62.
// XOR chunk swizzle (proven r9): phys chunk = logical ^ ((row>>1)&3) on the
// GLL *source* address (dest linear, rule 21); frag reads 2-way/bank = free.
// ---------------------------------------------------------------------------
#define NT (K_DIM / 64)

__global__ __launch_bounds__(512, 2) void f16gemm256_kernel(
    const uint8_t* __restrict__ xh,    // fp16 bits [M, K] (ws + 0)
    const uint8_t* __restrict__ wh,    // fp16 bits [N, K] (ws + 32MB)
    float* __restrict__ out)           // [M, N] float32
{
  __shared__ uint16_t Al[2][2][256 * 32];   // [buf][kh][row][chunk*8+e]
  __shared__ uint16_t Bl[2][2][256 * 32];

  const int tid  = threadIdx.x;
  const int lane = tid & 63;
  const int wave = tid >> 6;           // 0..7
  const int wm   = wave >> 2;          // 0..1  (128-row half of M tile)
  const int wn   = wave & 3;           // 0..3  (64-col quarter of N tile)

  // Bijective XCD swizzle: 256 blocks, 8 XCDs, 32 blocks each.
  const int bid = blockIdx.x;
  const int sw  = (bid & 7) * 32 + (bid >> 3);
  const int m0  = (sw >> 4) * 256;
  const int n0  = (sw & 15) * 256;

  // Staging geometry: slot = tid + s*512 over a 1024-slot (16 KB) region;
  // phys slot (row, cc) sources global chunk cc ^ ((row>>1)&3).
  const uint8_t* asrc[2];
  const uint8_t* bsrc[2];
  int ldst[2];
#pragma unroll
  for (int s = 0; s < 2; ++s) {
    const int slot = tid + s * 512;
    const int row  = slot >> 2;
    const int g    = (slot & 3) ^ ((row >> 1) & 3);
    asrc[s] = xh + ((size_t)(m0 + row) * K_DIM) * 2 + g * 16;
    bsrc[s] = wh + ((size_t)(n0 + row) * K_DIM) * 2 + g * 16;
    ldst[s] = slot * 16;
  }

  auto STAGE = [&](int isB, int buf, int kh, int tt) {
    const int koff  = tt * 128 + kh * 64;   // global k byte offset
    uint8_t* lb = (uint8_t*)(isB ? &Bl[0][0][0] : &Al[0][0][0]) +
                  (buf * 2 + kh) * 16384;
#pragma unroll
    for (int s = 0; s < 2; ++s) {
      const uint8_t* gp = (isB ? bsrc[s] : asrc[s]) + koff;
      __builtin_amdgcn_global_load_lds(
          (const __attribute__((address_space(1))) uint32_t*)gp,
          (__attribute__((address_space(3))) uint32_t*)(lb + ldst[s]), 16, 0, 0);
    }
  };

  // Per-thread fragment read offsets (u16 units within a (buf,kh) region).
  int aoff[8], boff[4];
#pragma unroll
  for (int m = 0; m < 8; ++m) {
    const int row = wm * 128 + m * 16 + (lane & 15);
    const int ch  = (lane >> 4) ^ ((row >> 1) & 3);
    aoff[m] = row * 32 + ch * 8;
  }
#pragma unroll
  for (int n = 0; n < 4; ++n) {
    const int row = wn * 64 + n * 16 + (lane & 15);
    const int ch  = (lane >> 4) ^ ((row >> 1) & 3);
    boff[n] = row * 32 + ch * 8;
  }

  f32x4 acc[8][4];
#pragma unroll
  for (int i = 0; i < 8; ++i)
#pragma unroll
    for (int j = 0; j < 4; ++j) acc[i][j] = (f32x4){0.f, 0.f, 0.f, 0.f};

  // Prologue: queue 6 half-tiles; vmcnt(8) retires {B0(0),A0(0)}.
  STAGE(1, 0, 0, 0);
  STAGE(0, 0, 0, 0);
  STAGE(1, 0, 1, 0);
  STAGE(0, 0, 1, 0);
  STAGE(1, 1, 0, 1);
  STAGE(0, 1, 0, 1);
  asm volatile("s_waitcnt vmcnt(8)" ::: "memory");
  __builtin_amdgcn_s_barrier();

  half8 af[8], bfr[4];

#pragma unroll 2
  for (int t = 0; t < NT; ++t) {
    const int cur = t & 1;
    const uint16_t* Ab = &Al[cur][0][0];
    const uint16_t* Bb = &Bl[cur][0][0];
    const bool st1 = (t + 1 < NT);
    const bool st2 = (t + 2 < NT);

    // ===== phase alpha: kh=0, 12 reads + 32 MFMA in ONE scheduling region =====
    __builtin_amdgcn_s_setprio(1);
#pragma unroll
    for (int n = 0; n < 4; ++n) bfr[n] = *(const half8*)(Bb + boff[n]);
#pragma unroll
    for (int m = 0; m < 8; ++m) af[m] = *(const half8*)(Ab + aoff[m]);
    if (st1) { STAGE(1, cur ^ 1, 1, t + 1); STAGE(0, cur ^ 1, 1, t + 1); }
    // no barrier here: compiler interleaves staged lgkmcnt(N) waits with MFMAs
#pragma unroll
    for (int m = 0; m < 8; ++m)
#pragma unroll
      for (int n = 0; n < 4; ++n)
        acc[m][n] = mfma16(af[m], bfr[n], acc[m][n]);
    __builtin_amdgcn_s_setprio(0);
    if (st1) asm volatile("s_waitcnt vmcnt(8)" ::: "memory");
    else     asm volatile("s_waitcnt vmcnt(0)" ::: "memory");
    __builtin_amdgcn_s_barrier();

    // ===== phase beta: kh=1 =====
    __builtin_amdgcn_s_setprio(1);
#pragma unroll
    for (int n = 0; n < 4; ++n) bfr[n] = *(const half8*)(Bb + 8192 + boff[n]);
#pragma unroll
    for (int m = 0; m < 8; ++m) af[m] = *(const half8*)(Ab + 8192 + aoff[m]);
    if (st2) { STAGE(1, cur, 0, t + 2); STAGE(0, cur, 0, t + 2); }
#pragma unroll
    for (int m = 0; m < 8; ++m)
#pragma unroll
      for (int n = 0; n < 4; ++n)
        acc[m][n] = mfma16(af[m], bfr[n], acc[m][n]);
    __builtin_amdgcn_s_setprio(0);
    if (st2)      asm volatile("s_waitcnt vmcnt(8)" ::: "memory");
    else if (st1) asm volatile("s_waitcnt vmcnt(4)" ::: "memory");
    __builtin_amdgcn_s_barrier();
  }

  // ---- Epilogue: C/D layout col(n) = lane&15, row(m) = (lane>>4)*4 + r ----
  const int mb = m0 + wm * 128 + (lane >> 4) * 4;
  const int nb = n0 + wn * 64 + (lane & 15);
#pragma unroll
  for (int m = 0; m < 8; ++m)
#pragma unroll
    for (int n = 0; n < 4; ++n)
#pragma unroll
      for (int r = 0; r < 4; ++r)
        out[(size_t)(mb + m * 16 + r) * N_DIM + (nb + n * 16)] = acc[m][n][r];
}

// ---------------------------------------------------------------------------
// Fallback (r9 champion): 128x128, in-loop B dequant — used only if d_ws is
// too small for both fp16 operands.
// ---------------------------------------------------------------------------
#define BM 128
#define BN 128
#define BK 32

__global__ __launch_bounds__(256, 2) void fp4gemm_kernel(
    const uint8_t* __restrict__ xh, const int* __restrict__ pw,
    const float* __restrict__ lutf, float* __restrict__ out)
{
  __shared__ uint16_t ldsA[BM * BK];
  __shared__ uint16_t ldsB[BN * BK];

  const int tid  = threadIdx.x;
  const int lane = tid & 63;
  const int wave = tid >> 6;
  const int wm   = wave >> 1;
  const int wn   = wave & 1;
  const int m0 = blockIdx.y * BM;
  const int n0 = blockIdx.x * BN;

  uint32_t ph, pl;
  lut_pool(lutf, ph, pl);

  f32x4 acc[4][4];
#pragma unroll
  for (int i = 0; i < 4; ++i)
#pragma unroll
    for (int j = 0; j < 4; ++j) acc[i][j] = (f32x4){0.f, 0.f, 0.f, 0.f};

  const int rowB  = tid >> 1;
  const int halfB = tid & 1;
  const int swzB  = (rowB >> 1) & 3;

  for (int kt = 0; kt < K_DIM / BK; ++kt) {
    __syncthreads();

#pragma unroll
    for (int s = 0; s < 2; ++s) {
      const int idx = tid + s * 256;
      const int row = idx >> 2;
      const int c16 = idx & 3;
      const int g16 = c16 ^ ((row >> 1) & 3);
      const uint8_t* gp = xh + ((size_t)(m0 + row) * K_DIM + kt * BK) * 2 + g16 * 16;
      uint8_t* lp = (uint8_t*)ldsA + (size_t)idx * 16;
      __builtin_amdgcn_global_load_lds(
          (const __attribute__((address_space(1))) uint32_t*)gp,
          (__attribute__((address_space(3))) uint32_t*)lp, 16, 0, 0);
    }

    {
      const int* gp = pw + (size_t)(n0 + rowB) * KW + kt * (BK / 2) + halfB * 8;
      const int4 wA = ((const int4*)gp)[0];
      const int4 wB = ((const int4*)gp)[1];
      uint8_t* base = (uint8_t*)ldsB + rowB * 64;
      *(uint4*)(base + ((halfB * 2 + 0) ^ swzB) * 16) =
          make_uint4(dq(wA.x, ph, pl), dq(wA.y, ph, pl),
                     dq(wA.z, ph, pl), dq(wA.w, ph, pl));
      *(uint4*)(base + ((halfB * 2 + 1) ^ swzB) * 16) =
          make_uint4(dq(wB.x, ph, pl), dq(wB.y, ph, pl),
                     dq(wB.z, ph, pl), dq(wB.w, ph, pl));
    }

    __syncthreads();

    const int q = lane >> 4;
    half8 af[4], bfr[4];
#pragma unroll
    for (int i = 0; i < 4; ++i) {
      const int row = wm * 64 + i * 16 + (lane & 15);
      af[i] = *(const half8*)(ldsA + row * BK + (q ^ ((row >> 1) & 3)) * 8);
    }
#pragma unroll
    for (int j = 0; j < 4; ++j) {
      const int row = wn * 64 + j * 16 + (lane & 15);
      bfr[j] = *(const half8*)(ldsB + row * BK + (q ^ ((row >> 1) & 3)) * 8);
    }
#pragma unroll
    for (int i = 0; i < 4; ++i)
#pragma unroll
      for (int j = 0; j < 4; ++j)
        acc[i][j] = __builtin_amdgcn_mfma_f32_16x16x32_f16(af[i], bfr[j], acc[i][j], 0, 0, 0);
  }

  const int mb = m0 + wm * 64 + (lane >> 4) * 4;
  const int nb = n0 + wn * 64 + (lane & 15);
#pragma unroll
  for (int i = 0; i < 4; ++i)
#pragma unroll
    for (int j = 0; j < 4; ++j)
#pragma unroll
      for (int r = 0; r < 4; ++r)
        out[(size_t)(mb + i * 16 + r) * N_DIM + (nb + j * 16)] = acc[i][j][r];
}

extern "C" void kernel_launch(void* const* d_in, const int* in_sizes, int n_in,
                              void* d_out, int out_size, void* d_ws, size_t ws_size,
                              hipStream_t stream) {
  // Size-based dispatch (element counts are dtype-independent and unique).
  const void* px = nullptr; const void* ppw = nullptr; const void* plut = nullptr;
  for (int i = 0; i < n_in; ++i) {
    const long s = in_sizes[i];
    if (s == (long)M_DIM * K_DIM) px = d_in[i];
    else if (s == (long)N_DIM * KW) ppw = d_in[i];
    else if (s == 16) plut = d_in[i];
  }
  if (!px || !ppw || !plut) { px = d_in[0]; ppw = d_in[1]; plut = d_in[2]; }

  if (ws_size >= WS_XH_BYTES + WS_WH_BYTES) {
    // Fused prep: x f32->f16 into ws[0,32MB) and W fp4->f16 into ws[32MB,64MB).
    uint8_t* wh = (uint8_t*)d_ws + WS_XH_BYTES;
    prep_kernel<<<XBLOCKS + WBLOCKS, 256, 0, stream>>>(
        (const float4*)px, (uint4*)d_ws, (const int4*)ppw, (uint4*)wh,
        (const float*)plut);
    f16gemm256_kernel<<<dim3(256), dim3(512), 0, stream>>>(
        (const uint8_t*)d_ws, wh, (float*)d_out);
  } else {
    cvt_x_kernel<<<(M_DIM * K_DIM / 8) / 256, 256, 0, stream>>>(
        (const float4*)px, (uint4*)d_ws);
    dim3 grid(N_DIM / BN, M_DIM / BM);
    fp4gemm_kernel<<<grid, dim3(256), 0, stream>>>(
        (const uint8_t*)d_ws, (const int*)ppw, (const float*)plut, (float*)d_out);
  }
}